// Round 1
// baseline (1901.175 us; speedup 1.0000x reference)
//
#include <hip/hip_runtime.h>
#include <math.h>

// ---------------- wavelet filter constants (bior-style, L=12) ----------------
#define W0f  (-0.00107730108499558f)
#define W1f  (0.004777257511010651f)
#define W2f  (0.0005538422009938016f)
#define W3f  (-0.031582039318031156f)
#define W4f  (0.02752286553001629f)
#define W5f  (0.09750160558707936f)
#define W6f  (-0.12976686756709563f)
#define W7f  (-0.22626469396516913f)
#define W8f  (0.3152503517092432f)
#define W9f  (0.7511339080215775f)
#define W10f (0.4946238903983854f)
#define W11f (0.11154074335008017f)

// KA0 = REC_LO = reverse(DEC_LO); KA1 = REC_HI = (-1)^n DEC_LO
// KS0 = DEC_LO; KS1 = DEC_HI = reverse(REC_HI)
__constant__ float cKA0[12] = {W11f,W10f,W9f,W8f,W7f,W6f,W5f,W4f,W3f,W2f,W1f,W0f};
__constant__ float cKA1[12] = {W0f,-W1f,W2f,-W3f,W4f,-W5f,W6f,-W7f,W8f,-W9f,W10f,-W11f};
__constant__ float cKS0[12] = {W0f,W1f,W2f,W3f,W4f,W5f,W6f,W7f,W8f,W9f,W10f,W11f};
__constant__ float cKS1[12] = {-W11f,W10f,-W9f,W8f,-W7f,W6f,-W5f,W4f,-W3f,W2f,-W1f,W0f};

__device__ __forceinline__ float gelu_f(float x) {
    return 0.5f * x * (1.0f + erff(x * 0.70710678118654752440f));
}

// ---------------- fc0 + concat + transpose + reflect pad(1) ----------------
// out: (B=8, C=32, 258, 258)
__global__ __launch_bounds__(256) void fc0_pad(
    const float* __restrict__ u, const float* __restrict__ par,
    const float* __restrict__ xg, const float* __restrict__ yg,
    const float* __restrict__ w, const float* __restrict__ bias,
    float* __restrict__ out) {
    __shared__ float sw[128];
    __shared__ float sb[32];
    int tid = threadIdx.x;
    if (tid < 128) sw[tid] = w[tid];
    if (tid < 32)  sb[tid] = bias[tid];
    __syncthreads();
    const int Hp = 258, S = 256;
    int gid = blockIdx.x * 256 + tid;
    int total = 8 * Hp * Hp;
    if (gid >= total) return;
    int b  = gid / (Hp * Hp), r = gid % (Hp * Hp);
    int yy = r / Hp, xx = r % Hp;
    int iy = yy - 1; iy = iy < 0 ? -iy : (iy >= S ? 2 * S - 2 - iy : iy);
    int ix = xx - 1; ix = ix < 0 ? -ix : (ix >= S ? 2 * S - 2 - ix : ix);
    float v0 = u  [(b * S + iy) * S + ix];
    float v1 = par[(b * S + iy) * S + ix];
    float v2 = xg [b * S + iy];
    float v3 = yg [b * S + ix];
    size_t base = (size_t)b * 32 * Hp * Hp + (size_t)yy * Hp + xx;
    #pragma unroll
    for (int o = 0; o < 32; o++) {
        out[base + (size_t)o * Hp * Hp] =
            sw[o*4] * v0 + sw[o*4+1] * v1 + sw[o*4+2] * v2 + sw[o*4+3] * v3 + sb[o];
    }
}

// ---------------- fused 2D analysis DWT (one level) ----------------
// in: (C, H, W) -> ll/lh/hl/hh: (C, Ho, Wo); Ho=H/2+5, Wo=W/2+5
// lh = (w-lo, h-hi), hl = (w-hi, h-lo)
__global__ __launch_bounds__(256) void dwt2d(
    const float* __restrict__ in, float* __restrict__ ll, float* __restrict__ lh,
    float* __restrict__ hl, float* __restrict__ hh, int H, int W, int Ho, int Wo) {
    int c   = blockIdx.z;
    int ty0 = blockIdx.y * 16;
    int tx0 = blockIdx.x * 16;
    const float* img = in + (size_t)c * H * W;
    __shared__ float sIn[42][44];
    __shared__ float rlo[42][17];
    __shared__ float rhi[42][17];
    int tid = threadIdx.x;
    for (int idx = tid; idx < 42 * 42; idx += 256) {
        int r = idx / 42, q = idx % 42;
        int gy = 2 * ty0 - 10 + r;
        int gx = 2 * tx0 - 10 + q;
        gy = gy < 0 ? -1 - gy : (gy >= H ? 2 * H - 1 - gy : gy);
        gx = gx < 0 ? -1 - gx : (gx >= W ? 2 * W - 1 - gx : gx);
        sIn[r][q] = img[gy * W + gx];
    }
    __syncthreads();
    for (int idx = tid; idx < 42 * 16; idx += 256) {
        int r = idx / 16, j = idx % 16;
        float alo = 0.f, ahi = 0.f;
        #pragma unroll
        for (int t = 0; t < 12; t++) {
            float v = sIn[r][2 * j + t];
            alo += v * cKA0[t];
            ahi += v * cKA1[t];
        }
        rlo[r][j] = alo; rhi[r][j] = ahi;
    }
    __syncthreads();
    int jy = tid / 16, jx = tid % 16;
    int oy = ty0 + jy, ox = tx0 + jx;
    if (oy < Ho && ox < Wo) {
        float a0 = 0.f, a1 = 0.f, a2 = 0.f, a3 = 0.f;
        #pragma unroll
        for (int t = 0; t < 12; t++) {
            float vl = rlo[2 * jy + t][jx];
            float vh = rhi[2 * jy + t][jx];
            a0 += vl * cKA0[t]; a1 += vl * cKA1[t];
            a2 += vh * cKA0[t]; a3 += vh * cKA1[t];
        }
        size_t o = (size_t)c * Ho * Wo + (size_t)oy * Wo + ox;
        ll[o] = a0; lh[o] = a1; hl[o] = a2; hh[o] = a3;
    }
}

// ---------------- fused 2D synthesis IDWT (one level) ----------------
// ll/lh/hl/hh: (C,h,w) -> out: (C, 2h-10, 2w-10); optional base add + gelu
__global__ __launch_bounds__(256) void idwt2d(
    const float* __restrict__ ll, const float* __restrict__ lh,
    const float* __restrict__ hl, const float* __restrict__ hh,
    float* out, const float* base, int h, int w, int Oh, int Ow, int do_gelu) {
    int c   = blockIdx.z;
    int my0 = blockIdx.y * 16;
    int nx0 = blockIdx.x * 16;
    __shared__ float sll[21][22], slh[21][22], shl[21][22], shh[21][22];
    __shared__ float sxl[32][22], sxh[32][22];
    int tid = threadIdx.x;
    size_t cb = (size_t)c * h * w;
    for (int idx = tid; idx < 21 * 21; idx += 256) {
        int r = idx / 21, q = idx % 21;
        int gy = min(my0 + r, h - 1);
        int gx = min(nx0 + q, w - 1);
        size_t g = cb + (size_t)gy * w + gx;
        sll[r][q] = ll[g]; slh[r][q] = lh[g];
        shl[r][q] = hl[g]; shh[r][q] = hh[g];
    }
    __syncthreads();
    // height synthesis: local out rows 0..31 (= 2m'+p), cols 0..20
    for (int idx = tid; idx < 32 * 21; idx += 256) {
        int r = idx / 21, q = idx % 21;
        int mp = r >> 1, p = r & 1;
        float al = 0.f, ah = 0.f;
        #pragma unroll
        for (int s = 0; s < 6; s++) {
            float k0 = cKS0[2 * s + 1 - p];
            float k1 = cKS1[2 * s + 1 - p];
            al += sll[mp + s][q] * k0 + slh[mp + s][q] * k1;
            ah += shl[mp + s][q] * k0 + shh[mp + s][q] * k1;
        }
        sxl[r][q] = al; sxh[r][q] = ah;
    }
    __syncthreads();
    // width synthesis: 32x32 out tile
    for (int idx = tid; idx < 32 * 32; idx += 256) {
        int r = idx / 32, q2 = idx % 32;
        int np = q2 >> 1, q = q2 & 1;
        int oy = 2 * my0 + r, ox = 2 * nx0 + q2;
        if (oy < Oh && ox < Ow) {
            float a = 0.f;
            #pragma unroll
            for (int s = 0; s < 6; s++) {
                float k0 = cKS0[2 * s + 1 - q];
                float k1 = cKS1[2 * s + 1 - q];
                a += sxl[r][np + s] * k0 + sxh[r][np + s] * k1;
            }
            size_t o = (size_t)c * Oh * Ow + (size_t)oy * Ow + ox;
            if (base) {
                a += base[o];
                if (do_gelu) a = gelu_f(a);
            }
            out[o] = a;
        }
    }
}

// ---------------- pointwise 32x32 channel mix, in place ----------------
// h: (B,32,HW); out[b,o,p] = sum_i pw[o,i]*h[b,i,p] + pb[o]
__global__ __launch_bounds__(256) void pw_inplace(
    float* __restrict__ h, const float* __restrict__ w, const float* __restrict__ b,
    int HW, int npix) {
    __shared__ float sw[1024];
    __shared__ float sb[32];
    int tid = threadIdx.x;
    for (int i = tid; i < 1024; i += 256) sw[i] = w[i];
    if (tid < 32) sb[tid] = b[tid];
    __syncthreads();
    int gid = blockIdx.x * 256 + tid;
    if (gid >= npix) return;
    int bb = gid / HW, p = gid % HW;
    float* hb = h + (size_t)bb * 32 * HW + p;
    float acc[32];
    #pragma unroll
    for (int o = 0; o < 32; o++) acc[o] = sb[o];
    for (int i = 0; i < 32; i++) {
        float v = hb[(size_t)i * HW];
        #pragma unroll
        for (int o = 0; o < 32; o++) acc[o] += sw[o * 32 + i] * v;
    }
    #pragma unroll
    for (int o = 0; o < 32; o++) hb[(size_t)o * HW] = acc[o];
}

// ---------------- bilinear interp of (32,32,64,64) weights ----------------
// out layout: [Ho][Wo][i(32)][o(32)]
__global__ __launch_bounds__(256) void interp_w(
    const float* __restrict__ w, float* __restrict__ outw, int Ho, int Wo) {
    int gid = blockIdx.x * 256 + threadIdx.x;
    int total = Ho * Wo * 1024;
    if (gid >= total) return;
    int o = gid & 31, i = (gid >> 5) & 31;
    int rest = gid >> 10;
    int x = rest % Wo, y = rest / Wo;
    float sy = fmaxf((y + 0.5f) * (64.0f / Ho) - 0.5f, 0.0f);
    int y0 = min((int)sy, 63), y1 = min(y0 + 1, 63);
    float ty = fminf(sy - (float)y0, 1.0f);
    float sx = fmaxf((x + 0.5f) * (64.0f / Wo) - 0.5f, 0.0f);
    int x0 = min((int)sx, 63), x1 = min(x0 + 1, 63);
    float tx = fminf(sx - (float)x0, 1.0f);
    const float* wb = w + ((size_t)(i * 32 + o)) * 4096;
    float a = wb[y0 * 64 + x0] * (1.f - ty) + wb[y1 * 64 + x0] * ty;
    float c = wb[y0 * 64 + x1] * (1.f - ty) + wb[y1 * 64 + x1] * ty;
    outw[gid] = a * (1.f - tx) + c * tx;
}

// ---------------- ll channel mix, in place ----------------
// ll: (B,32,A); wi: [A][32i][32o]; one block per pixel p
__global__ __launch_bounds__(256) void mix_ll(
    float* __restrict__ ll, const float* __restrict__ wi, int A) {
    int p = blockIdx.x;
    __shared__ float sw[1024];
    __shared__ float sv[256];
    int tid = threadIdx.x;
    const float* wb = wi + (size_t)p * 1024;
    for (int k = tid; k < 1024; k += 256) sw[k] = wb[k];
    int b = tid >> 5, i = tid & 31;
    sv[tid] = ll[((size_t)(b * 32 + i)) * A + p];
    __syncthreads();
    float acc = 0.f;
    #pragma unroll
    for (int k = 0; k < 32; k++) acc += sv[b * 32 + k] * sw[k * 32 + i];
    ll[((size_t)(b * 32 + i)) * A + p] = acc;
}

// ---------------- high-band channel mix, in place ----------------
// hb: one subband (B,32,Hs,Ws); wi: [Hs][32i][32o] (already offset to this subband)
// grid: (Hs, B)
__global__ __launch_bounds__(256) void mix_high(
    float* __restrict__ hb, const float* __restrict__ wi, int Hs, int Ws) {
    int y = blockIdx.x;
    int b = blockIdx.y;
    __shared__ float sw[1024];
    __shared__ float sv[256]; // [i(32)][xc(8)]
    int tid = threadIdx.x;
    const float* wb = wi + (size_t)y * 1024;
    for (int k = tid; k < 1024; k += 256) sw[k] = wb[k];
    size_t rowbase = ((size_t)(b * 32) * Hs + y) * Ws;
    size_t cstride = (size_t)Hs * Ws;
    int ch = tid >> 3, xc = tid & 7;
    for (int x0 = 0; x0 < Ws; x0 += 8) {
        int xl = x0 + xc;
        float v = 0.f;
        if (xl < Ws) v = hb[rowbase + (size_t)ch * cstride + xl];
        sv[tid] = v;
        __syncthreads();
        float acc = 0.f;
        #pragma unroll
        for (int k = 0; k < 32; k++) acc += sv[k * 8 + xc] * sw[k * 32 + ch];
        if (xl < Ws) hb[rowbase + (size_t)ch * cstride + xl] = acc;
        __syncthreads();
    }
}

// ---------------- head: crop + fc1 + gelu + fc2 ----------------
__global__ __launch_bounds__(256) void head_k(
    const float* __restrict__ h, const float* __restrict__ w1, const float* __restrict__ b1,
    const float* __restrict__ w2, const float* __restrict__ b2, float* __restrict__ out) {
    __shared__ float sw1[4096];
    __shared__ float sb1[128];
    __shared__ float sw2[128];
    int tid = threadIdx.x;
    for (int k = tid; k < 4096; k += 256) sw1[k] = w1[k];
    if (tid < 128) { sb1[tid] = b1[tid]; sw2[tid] = w2[tid]; }
    __syncthreads();
    int gid = blockIdx.x * 256 + tid;
    if (gid >= 8 * 256 * 256) return;
    int b = gid >> 16, r = gid & 65535;
    int yy = r >> 8, xx = r & 255;
    const int Hp = 258;
    size_t base = (size_t)b * 32 * Hp * Hp + (size_t)(yy + 1) * Hp + (xx + 1);
    float in[32];
    #pragma unroll
    for (int i = 0; i < 32; i++) in[i] = h[base + (size_t)i * Hp * Hp];
    float acc = b2[0];
    for (int j = 0; j < 128; j++) {
        float hj = sb1[j];
        #pragma unroll
        for (int i = 0; i < 32; i++) hj += sw1[j * 32 + i] * in[i];
        acc += sw2[j] * gelu_f(hj);
    }
    out[gid] = acc;
}

extern "C" void kernel_launch(void* const* d_in, const int* in_sizes, int n_in,
                              void* d_out, int out_size, void* d_ws, size_t ws_size,
                              hipStream_t stream) {
    (void)in_sizes; (void)n_in; (void)out_size;
    const float* u    = (const float*)d_in[0];
    const float* par  = (const float*)d_in[1];
    const float* xg   = (const float*)d_in[2];
    const float* yg   = (const float*)d_in[3];
    const float* fc0w = (const float*)d_in[4];
    const float* fc0b = (const float*)d_in[5];
    const float* wcw  = (const float*)d_in[6];
    const float* pww  = (const float*)d_in[7];
    const float* pwb  = (const float*)d_in[8];
    const float* fc1w = (const float*)d_in[9];
    const float* fc1b = (const float*)d_in[10];
    const float* fc2w = (const float*)d_in[11];
    const float* fc2b = (const float*)d_in[12];
    float* out = (float*)d_out;
    float* ws  = (float*)d_ws;

    const int Hp = 258;
    const size_t HW = (size_t)Hp * Hp;        // 66564
    const size_t NH = 256 * HW;               // (B*32) images
    const int S1 = 134, S2 = 72, S3 = 41;
    const size_t A1 = (size_t)S1 * S1, N1 = 256 * A1;
    const size_t A2 = (size_t)S2 * S2, N2 = 256 * A2;
    const size_t A3 = (size_t)S3 * S3, N3 = 256 * A3;

    float* H   = ws;
    float* ll1 = H   + NH;   // also reused as out2 (C,134,134)
    float* lh1 = ll1 + N1;
    float* hl1 = lh1 + N1;
    float* hh1 = hl1 + N1;
    float* ll2 = hh1 + N1;   // also reused as out3 (C,72,72)
    float* lh2 = ll2 + N2;
    float* hl2 = lh2 + N2;
    float* hh2 = hl2 + N2;
    float* ll3 = hh2 + N2;
    float* lh3 = ll3 + N3;
    float* hl3 = lh3 + N3;
    float* hh3 = hl3 + N3;
    float* wll = hh3 + N3;                       // 41*41*1024
    float* wh1 = wll + (size_t)S3 * S3 * 1024;   // 3*134*1024
    float* wh2 = wh1 + (size_t)3 * S1 * 1024;    // 3*72*1024
    float* wh3 = wh2 + (size_t)3 * S2 * 1024;    // 3*41*1024
    size_t needed = (size_t)(wh3 + (size_t)3 * S3 * 1024 - ws) * sizeof(float);
    if (ws_size < needed) return;

    const int npix = 8 * (int)HW; // 532512
    fc0_pad<<<(npix + 255) / 256, 256, 0, stream>>>(u, par, xg, yg, fc0w, fc0b, H);

    for (int l = 0; l < 4; l++) {
        const float* wl = wcw + (size_t)l * 32 * 32 * 64 * 64;
        interp_w<<<((int)(A3 * 1024) + 255) / 256, 256, 0, stream>>>(wl, wll, S3, S3);
        interp_w<<<(3 * S1 * 1024 + 255) / 256, 256, 0, stream>>>(wl, wh1, 3, S1);
        interp_w<<<(3 * S2 * 1024 + 255) / 256, 256, 0, stream>>>(wl, wh2, 3, S2);
        interp_w<<<(3 * S3 * 1024 + 255) / 256, 256, 0, stream>>>(wl, wh3, 3, S3);

        // analysis (reads H before pw overwrites it)
        dwt2d<<<dim3((S1 + 15) / 16, (S1 + 15) / 16, 256), 256, 0, stream>>>(
            H, ll1, lh1, hl1, hh1, Hp, Hp, S1, S1);
        dwt2d<<<dim3((S2 + 15) / 16, (S2 + 15) / 16, 256), 256, 0, stream>>>(
            ll1, ll2, lh2, hl2, hh2, S1, S1, S2, S2);
        dwt2d<<<dim3((S3 + 15) / 16, (S3 + 15) / 16, 256), 256, 0, stream>>>(
            ll2, ll3, lh3, hl3, hh3, S2, S2, S3, S3);

        // u2 = pw(h) in place
        pw_inplace<<<(npix + 255) / 256, 256, 0, stream>>>(
            H, pww + (size_t)l * 1024, pwb + (size_t)l * 32, (int)HW, npix);

        // subband channel mixes (in place)
        mix_ll<<<(int)A3, 256, 0, stream>>>(ll3, wll, (int)A3);
        mix_high<<<dim3(S3, 8), 256, 0, stream>>>(lh3, wh3 + (size_t)0 * S3 * 1024, S3, S3);
        mix_high<<<dim3(S3, 8), 256, 0, stream>>>(hl3, wh3 + (size_t)1 * S3 * 1024, S3, S3);
        mix_high<<<dim3(S3, 8), 256, 0, stream>>>(hh3, wh3 + (size_t)2 * S3 * 1024, S3, S3);
        mix_high<<<dim3(S2, 8), 256, 0, stream>>>(lh2, wh2 + (size_t)0 * S2 * 1024, S2, S2);
        mix_high<<<dim3(S2, 8), 256, 0, stream>>>(hl2, wh2 + (size_t)1 * S2 * 1024, S2, S2);
        mix_high<<<dim3(S2, 8), 256, 0, stream>>>(hh2, wh2 + (size_t)2 * S2 * 1024, S2, S2);
        mix_high<<<dim3(S1, 8), 256, 0, stream>>>(lh1, wh1 + (size_t)0 * S1 * 1024, S1, S1);
        mix_high<<<dim3(S1, 8), 256, 0, stream>>>(hl1, wh1 + (size_t)1 * S1 * 1024, S1, S1);
        mix_high<<<dim3(S1, 8), 256, 0, stream>>>(hh1, wh1 + (size_t)2 * S1 * 1024, S1, S1);

        // synthesis; out3 -> ll2 buffer, out2 -> ll1 buffer, final adds into H (+gelu)
        idwt2d<<<dim3((S2 + 31) / 32, (S2 + 31) / 32, 256), 256, 0, stream>>>(
            ll3, lh3, hl3, hh3, ll2, nullptr, S3, S3, S2, S2, 0);
        idwt2d<<<dim3((S1 + 31) / 32, (S1 + 31) / 32, 256), 256, 0, stream>>>(
            ll2, lh2, hl2, hh2, ll1, nullptr, S2, S2, S1, S1, 0);
        idwt2d<<<dim3((Hp + 31) / 32, (Hp + 31) / 32, 256), 256, 0, stream>>>(
            ll1, lh1, hl1, hh1, H, H, S1, S1, Hp, Hp, (l < 3) ? 1 : 0);
    }

    head_k<<<(8 * 256 * 256) / 256, 256, 0, stream>>>(H, fc1w, fc1b, fc2w, fc2b, out);
}

// Round 2
// 1534.094 us; speedup vs baseline: 1.2393x; 1.2393x over previous
//
#include <hip/hip_runtime.h>
#include <math.h>

// ---------------- wavelet filter constants (bior-style, L=12) ----------------
#define W0f  (-0.00107730108499558f)
#define W1f  (0.004777257511010651f)
#define W2f  (0.0005538422009938016f)
#define W3f  (-0.031582039318031156f)
#define W4f  (0.02752286553001629f)
#define W5f  (0.09750160558707936f)
#define W6f  (-0.12976686756709563f)
#define W7f  (-0.22626469396516913f)
#define W8f  (0.3152503517092432f)
#define W9f  (0.7511339080215775f)
#define W10f (0.4946238903983854f)
#define W11f (0.11154074335008017f)

// KA0 = REC_LO = reverse(DEC_LO); KA1 = REC_HI = (-1)^n DEC_LO
// KS0 = DEC_LO; KS1 = DEC_HI = reverse(REC_HI)
__constant__ float cKA0[12] = {W11f,W10f,W9f,W8f,W7f,W6f,W5f,W4f,W3f,W2f,W1f,W0f};
__constant__ float cKA1[12] = {W0f,-W1f,W2f,-W3f,W4f,-W5f,W6f,-W7f,W8f,-W9f,W10f,-W11f};
__constant__ float cKS0[12] = {W0f,W1f,W2f,W3f,W4f,W5f,W6f,W7f,W8f,W9f,W10f,W11f};
__constant__ float cKS1[12] = {-W11f,W10f,-W9f,W8f,-W7f,W6f,-W5f,W4f,-W3f,W2f,-W1f,W0f};

__device__ __forceinline__ float gelu_f(float x) {
    return 0.5f * x * (1.0f + erff(x * 0.70710678118654752440f));
}

// ---------------- fc0 + concat + transpose + reflect pad(1) ----------------
__global__ __launch_bounds__(256) void fc0_pad(
    const float* __restrict__ u, const float* __restrict__ par,
    const float* __restrict__ xg, const float* __restrict__ yg,
    const float* __restrict__ w, const float* __restrict__ bias,
    float* __restrict__ out) {
    __shared__ float sw[128];
    __shared__ float sb[32];
    int tid = threadIdx.x;
    if (tid < 128) sw[tid] = w[tid];
    if (tid < 32)  sb[tid] = bias[tid];
    __syncthreads();
    const int Hp = 258, S = 256;
    int gid = blockIdx.x * 256 + tid;
    int total = 8 * Hp * Hp;
    if (gid >= total) return;
    int b  = gid / (Hp * Hp), r = gid % (Hp * Hp);
    int yy = r / Hp, xx = r % Hp;
    int iy = yy - 1; iy = iy < 0 ? -iy : (iy >= S ? 2 * S - 2 - iy : iy);
    int ix = xx - 1; ix = ix < 0 ? -ix : (ix >= S ? 2 * S - 2 - ix : ix);
    float v0 = u  [(b * S + iy) * S + ix];
    float v1 = par[(b * S + iy) * S + ix];
    float v2 = xg [b * S + iy];
    float v3 = yg [b * S + ix];
    size_t base = (size_t)b * 32 * Hp * Hp + (size_t)yy * Hp + xx;
    #pragma unroll
    for (int o = 0; o < 32; o++) {
        out[base + (size_t)o * Hp * Hp] =
            sw[o*4] * v0 + sw[o*4+1] * v1 + sw[o*4+2] * v2 + sw[o*4+3] * v3 + sb[o];
    }
}

// ---------------- fused 2D analysis DWT (one level) ----------------
__global__ __launch_bounds__(256) void dwt2d(
    const float* __restrict__ in, float* __restrict__ ll, float* __restrict__ lh,
    float* __restrict__ hl, float* __restrict__ hh, int H, int W, int Ho, int Wo) {
    int c   = blockIdx.z;
    int ty0 = blockIdx.y * 16;
    int tx0 = blockIdx.x * 16;
    const float* img = in + (size_t)c * H * W;
    __shared__ float sIn[42][44];
    __shared__ float rlo[42][17];
    __shared__ float rhi[42][17];
    int tid = threadIdx.x;
    for (int idx = tid; idx < 42 * 42; idx += 256) {
        int r = idx / 42, q = idx % 42;
        int gy = 2 * ty0 - 10 + r;
        int gx = 2 * tx0 - 10 + q;
        gy = gy < 0 ? -1 - gy : (gy >= H ? 2 * H - 1 - gy : gy);
        gx = gx < 0 ? -1 - gx : (gx >= W ? 2 * W - 1 - gx : gx);
        sIn[r][q] = img[gy * W + gx];
    }
    __syncthreads();
    for (int idx = tid; idx < 42 * 16; idx += 256) {
        int r = idx / 16, j = idx % 16;
        float alo = 0.f, ahi = 0.f;
        #pragma unroll
        for (int t = 0; t < 12; t++) {
            float v = sIn[r][2 * j + t];
            alo += v * cKA0[t];
            ahi += v * cKA1[t];
        }
        rlo[r][j] = alo; rhi[r][j] = ahi;
    }
    __syncthreads();
    int jy = tid / 16, jx = tid % 16;
    int oy = ty0 + jy, ox = tx0 + jx;
    if (oy < Ho && ox < Wo) {
        float a0 = 0.f, a1 = 0.f, a2 = 0.f, a3 = 0.f;
        #pragma unroll
        for (int t = 0; t < 12; t++) {
            float vl = rlo[2 * jy + t][jx];
            float vh = rhi[2 * jy + t][jx];
            a0 += vl * cKA0[t]; a1 += vl * cKA1[t];
            a2 += vh * cKA0[t]; a3 += vh * cKA1[t];
        }
        size_t o = (size_t)c * Ho * Wo + (size_t)oy * Wo + ox;
        ll[o] = a0; lh[o] = a1; hl[o] = a2; hh[o] = a3;
    }
}

// ---------------- fused 2D synthesis IDWT (one level) ----------------
__global__ __launch_bounds__(256) void idwt2d(
    const float* __restrict__ ll, const float* __restrict__ lh,
    const float* __restrict__ hl, const float* __restrict__ hh,
    float* out, const float* base, int h, int w, int Oh, int Ow, int do_gelu) {
    int c   = blockIdx.z;
    int my0 = blockIdx.y * 16;
    int nx0 = blockIdx.x * 16;
    __shared__ float sll[21][22], slh[21][22], shl[21][22], shh[21][22];
    __shared__ float sxl[32][22], sxh[32][22];
    int tid = threadIdx.x;
    size_t cb = (size_t)c * h * w;
    for (int idx = tid; idx < 21 * 21; idx += 256) {
        int r = idx / 21, q = idx % 21;
        int gy = min(my0 + r, h - 1);
        int gx = min(nx0 + q, w - 1);
        size_t g = cb + (size_t)gy * w + gx;
        sll[r][q] = ll[g]; slh[r][q] = lh[g];
        shl[r][q] = hl[g]; shh[r][q] = hh[g];
    }
    __syncthreads();
    for (int idx = tid; idx < 32 * 21; idx += 256) {
        int r = idx / 21, q = idx % 21;
        int mp = r >> 1, p = r & 1;
        float al = 0.f, ah = 0.f;
        #pragma unroll
        for (int s = 0; s < 6; s++) {
            float k0 = cKS0[2 * s + 1 - p];
            float k1 = cKS1[2 * s + 1 - p];
            al += sll[mp + s][q] * k0 + slh[mp + s][q] * k1;
            ah += shl[mp + s][q] * k0 + shh[mp + s][q] * k1;
        }
        sxl[r][q] = al; sxh[r][q] = ah;
    }
    __syncthreads();
    for (int idx = tid; idx < 32 * 32; idx += 256) {
        int r = idx / 32, q2 = idx % 32;
        int np = q2 >> 1, q = q2 & 1;
        int oy = 2 * my0 + r, ox = 2 * nx0 + q2;
        if (oy < Oh && ox < Ow) {
            float a = 0.f;
            #pragma unroll
            for (int s = 0; s < 6; s++) {
                float k0 = cKS0[2 * s + 1 - q];
                float k1 = cKS1[2 * s + 1 - q];
                a += sxl[r][np + s] * k0 + sxh[r][np + s] * k1;
            }
            size_t o = (size_t)c * Oh * Ow + (size_t)oy * Ow + ox;
            if (base) {
                a += base[o];
                if (do_gelu) a = gelu_f(a);
            }
            out[o] = a;
        }
    }
}

// ---------------- pointwise 32x32 channel mix, in place ----------------
__global__ __launch_bounds__(256) void pw_inplace(
    float* __restrict__ h, const float* __restrict__ w, const float* __restrict__ b,
    int HW, int npix) {
    __shared__ float swT[1024];   // [i][o]
    __shared__ float sb[32];
    int tid = threadIdx.x;
    for (int k = tid; k < 1024; k += 256) { int o = k >> 5, i = k & 31; swT[i * 32 + o] = w[k]; }
    if (tid < 32) sb[tid] = b[tid];
    __syncthreads();
    int gid = blockIdx.x * 256 + tid;
    if (gid >= npix) return;
    int bb = gid / HW, p = gid % HW;
    float* hb = h + (size_t)bb * 32 * HW + p;
    float acc[32];
    #pragma unroll
    for (int o = 0; o < 32; o++) acc[o] = sb[o];
    for (int i = 0; i < 32; i++) {
        float v = hb[(size_t)i * HW];
        #pragma unroll
        for (int o4 = 0; o4 < 8; o4++) {
            float4 w4 = *(const float4*)&swT[i * 32 + o4 * 4];
            acc[o4*4+0] += v * w4.x; acc[o4*4+1] += v * w4.y;
            acc[o4*4+2] += v * w4.z; acc[o4*4+3] += v * w4.w;
        }
    }
    #pragma unroll
    for (int o = 0; o < 32; o++) hb[(size_t)o * HW] = acc[o];
}

// ---------------- transpose weight layer: [1024 io][4096 yx] -> [4096 yx][1024 io] ----------------
__global__ __launch_bounds__(256) void transpose_w(
    const float* __restrict__ w, float* __restrict__ wT) {
    __shared__ float t[64][65];
    int bx = blockIdx.x * 64; // yx
    int by = blockIdx.y * 64; // io
    int tid = threadIdx.x;
    for (int idx = tid; idx < 4096; idx += 256) {
        int r = idx >> 6, q = idx & 63;
        t[r][q] = w[(size_t)(by + r) * 4096 + bx + q];
    }
    __syncthreads();
    for (int idx = tid; idx < 4096; idx += 256) {
        int r = idx >> 6, q = idx & 63;
        wT[(size_t)(bx + r) * 1024 + by + q] = t[q][r];
    }
}

// ---------------- bilinear interp from transposed weights ----------------
// wT: [64*64][1024]; out: [Ho*Wo][1024]; one block per output pixel, coalesced.
__global__ __launch_bounds__(256) void interp_wT(
    const float* __restrict__ wT, float* __restrict__ outw, int Ho, int Wo) {
    int p = blockIdx.x;
    int y = p / Wo, x = p % Wo;
    float sy = fmaxf((y + 0.5f) * (64.0f / Ho) - 0.5f, 0.0f);
    int y0 = min((int)sy, 63), y1 = min(y0 + 1, 63);
    float ty = fminf(sy - (float)y0, 1.0f);
    float sx = fmaxf((x + 0.5f) * (64.0f / Wo) - 0.5f, 0.0f);
    int x0 = min((int)sx, 63), x1 = min(x0 + 1, 63);
    float tx = fminf(sx - (float)x0, 1.0f);
    float c00 = (1.f - ty) * (1.f - tx), c01 = (1.f - ty) * tx;
    float c10 = ty * (1.f - tx),         c11 = ty * tx;
    const float4* s00 = (const float4*)(wT + (size_t)(y0 * 64 + x0) * 1024);
    const float4* s01 = (const float4*)(wT + (size_t)(y0 * 64 + x1) * 1024);
    const float4* s10 = (const float4*)(wT + (size_t)(y1 * 64 + x0) * 1024);
    const float4* s11 = (const float4*)(wT + (size_t)(y1 * 64 + x1) * 1024);
    float4* op = (float4*)(outw + (size_t)p * 1024);
    int k = threadIdx.x; // 256 threads x float4 = 1024 floats
    float4 a = s00[k], b = s01[k], c = s10[k], d = s11[k];
    float4 r;
    r.x = c00*a.x + c01*b.x + c10*c.x + c11*d.x;
    r.y = c00*a.y + c01*b.y + c10*c.y + c11*d.y;
    r.z = c00*a.z + c01*b.z + c10*c.z + c11*d.z;
    r.w = c00*a.w + c01*b.w + c10*c.w + c11*d.w;
    op[k] = r;
}

// ---------------- ll channel mix, in place ----------------
__global__ __launch_bounds__(256) void mix_ll(
    float* __restrict__ ll, const float* __restrict__ wi, int A) {
    int p = blockIdx.x;
    __shared__ float sw[1024];
    __shared__ float sv[256];
    int tid = threadIdx.x;
    const float* wb = wi + (size_t)p * 1024;
    for (int k = tid; k < 1024; k += 256) sw[k] = wb[k];
    int b = tid >> 5, i = tid & 31;
    sv[tid] = ll[((size_t)(b * 32 + i)) * A + p];
    __syncthreads();
    float acc = 0.f;
    #pragma unroll
    for (int k = 0; k < 32; k++) acc += sv[b * 32 + k] * sw[k * 32 + i];
    ll[((size_t)(b * 32 + i)) * A + p] = acc;
}

// ---------------- high-band channel mix, 3 subbands, thread-per-pixel ----------------
// bands: lh|hl|hh contiguous, each (B,32,Hs,Ws), stride bandStride floats
// wi: [3][Hs][1024]
__global__ __launch_bounds__(256) void mix_high3(
    float* __restrict__ bands, const float* __restrict__ wi,
    int Hs, int Ws, size_t bandStride) {
    int s = blockIdx.z, y = blockIdx.y;
    float* hb = bands + (size_t)s * bandStride;
    const float* wb = wi + ((size_t)s * Hs + y) * 1024;
    __shared__ float sw[1024];
    int tid = threadIdx.x;
    for (int k = tid; k < 1024; k += 256) sw[k] = wb[k];
    __syncthreads();
    int q = blockIdx.x * 256 + tid;
    if (q >= 8 * Ws) return;
    int b = q / Ws, x = q % Ws;
    size_t base = ((size_t)(b * 32) * Hs + y) * Ws + x;
    size_t cs = (size_t)Hs * Ws;
    float acc[32];
    #pragma unroll
    for (int o = 0; o < 32; o++) acc[o] = 0.f;
    for (int i = 0; i < 32; i++) {
        float v = hb[base + (size_t)i * cs];
        #pragma unroll
        for (int o4 = 0; o4 < 8; o4++) {
            float4 w4 = *(const float4*)&sw[i * 32 + o4 * 4];
            acc[o4*4+0] += v * w4.x; acc[o4*4+1] += v * w4.y;
            acc[o4*4+2] += v * w4.z; acc[o4*4+3] += v * w4.w;
        }
    }
    #pragma unroll
    for (int o = 0; o < 32; o++) hb[base + (size_t)o * cs] = acc[o];
}

// ---------------- head: crop + fc1 + gelu + fc2, 4 px/thread ----------------
__global__ __launch_bounds__(256) void head_k(
    const float* __restrict__ h, const float* __restrict__ w1, const float* __restrict__ b1,
    const float* __restrict__ w2, const float* __restrict__ b2, float* __restrict__ out) {
    __shared__ float sw1[4096];
    __shared__ float sb1[128];
    __shared__ float sw2[128];
    int tid = threadIdx.x;
    for (int k = tid; k < 4096; k += 256) sw1[k] = w1[k];
    if (tid < 128) { sb1[tid] = b1[tid]; sw2[tid] = w2[tid]; }
    __syncthreads();
    const int Hp = 258;
    const int QP = 131072; // 8*256*256/4
    int g0 = blockIdx.x * 256 + tid;
    float in[4][32];
    #pragma unroll
    for (int p = 0; p < 4; p++) {
        int gid = g0 + p * QP;
        int b = gid >> 16, r = gid & 65535;
        int yy = r >> 8, xx = r & 255;
        size_t base = (size_t)b * 32 * Hp * Hp + (size_t)(yy + 1) * Hp + (xx + 1);
        #pragma unroll
        for (int i = 0; i < 32; i++) in[p][i] = h[base + (size_t)i * Hp * Hp];
    }
    float acc0 = 0.f, acc1 = 0.f, acc2 = 0.f, acc3 = 0.f;
    for (int j = 0; j < 128; j++) {
        float bj = sb1[j];
        float h0 = bj, h1 = bj, h2 = bj, h3 = bj;
        #pragma unroll
        for (int i4 = 0; i4 < 8; i4++) {
            float4 wv = *(const float4*)&sw1[j * 32 + i4 * 4];
            h0 += wv.x * in[0][i4*4+0] + wv.y * in[0][i4*4+1] + wv.z * in[0][i4*4+2] + wv.w * in[0][i4*4+3];
            h1 += wv.x * in[1][i4*4+0] + wv.y * in[1][i4*4+1] + wv.z * in[1][i4*4+2] + wv.w * in[1][i4*4+3];
            h2 += wv.x * in[2][i4*4+0] + wv.y * in[2][i4*4+1] + wv.z * in[2][i4*4+2] + wv.w * in[2][i4*4+3];
            h3 += wv.x * in[3][i4*4+0] + wv.y * in[3][i4*4+1] + wv.z * in[3][i4*4+2] + wv.w * in[3][i4*4+3];
        }
        float w2j = sw2[j];
        acc0 += w2j * gelu_f(h0);
        acc1 += w2j * gelu_f(h1);
        acc2 += w2j * gelu_f(h2);
        acc3 += w2j * gelu_f(h3);
    }
    float b2v = b2[0];
    out[g0          ] = acc0 + b2v;
    out[g0 +     QP ] = acc1 + b2v;
    out[g0 + 2 * QP ] = acc2 + b2v;
    out[g0 + 3 * QP ] = acc3 + b2v;
}

extern "C" void kernel_launch(void* const* d_in, const int* in_sizes, int n_in,
                              void* d_out, int out_size, void* d_ws, size_t ws_size,
                              hipStream_t stream) {
    (void)in_sizes; (void)n_in; (void)out_size;
    const float* u    = (const float*)d_in[0];
    const float* par  = (const float*)d_in[1];
    const float* xg   = (const float*)d_in[2];
    const float* yg   = (const float*)d_in[3];
    const float* fc0w = (const float*)d_in[4];
    const float* fc0b = (const float*)d_in[5];
    const float* wcw  = (const float*)d_in[6];
    const float* pww  = (const float*)d_in[7];
    const float* pwb  = (const float*)d_in[8];
    const float* fc1w = (const float*)d_in[9];
    const float* fc1b = (const float*)d_in[10];
    const float* fc2w = (const float*)d_in[11];
    const float* fc2b = (const float*)d_in[12];
    float* out = (float*)d_out;
    float* ws  = (float*)d_ws;

    const int Hp = 258;
    const size_t HW = (size_t)Hp * Hp;
    const size_t NH = 256 * HW;
    const int S1 = 134, S2 = 72, S3 = 41;
    const size_t A1 = (size_t)S1 * S1, N1 = 256 * A1;
    const size_t A2 = (size_t)S2 * S2, N2 = 256 * A2;
    const size_t A3 = (size_t)S3 * S3, N3 = 256 * A3;

    float* H   = ws;
    float* ll1 = H   + NH;
    float* lh1 = ll1 + N1;   // also reused as wT scratch (needs 4.19M <= N1=4.59M floats)
    float* hl1 = lh1 + N1;
    float* hh1 = hl1 + N1;
    float* ll2 = hh1 + N1;
    float* lh2 = ll2 + N2;
    float* hl2 = lh2 + N2;
    float* hh2 = hl2 + N2;
    float* ll3 = hh2 + N2;
    float* lh3 = ll3 + N3;
    float* hl3 = lh3 + N3;
    float* hh3 = hl3 + N3;
    float* wll = hh3 + N3;
    float* wh1 = wll + (size_t)S3 * S3 * 1024;
    float* wh2 = wh1 + (size_t)3 * S1 * 1024;
    float* wh3 = wh2 + (size_t)3 * S2 * 1024;
    size_t needed = (size_t)(wh3 + (size_t)3 * S3 * 1024 - ws) * sizeof(float);
    if (ws_size < needed) return;

    const int npix = 8 * (int)HW;
    fc0_pad<<<(npix + 255) / 256, 256, 0, stream>>>(u, par, xg, yg, fc0w, fc0b, H);

    for (int l = 0; l < 4; l++) {
        const float* wl = wcw + (size_t)l * 32 * 32 * 64 * 64;
        float* wT = lh1; // dead until dwt2d L1 writes it

        transpose_w<<<dim3(64, 16), 256, 0, stream>>>(wl, wT);
        interp_wT<<<S3 * S3, 256, 0, stream>>>(wT, wll, S3, S3);
        interp_wT<<<3 * S1,  256, 0, stream>>>(wT, wh1, 3, S1);
        interp_wT<<<3 * S2,  256, 0, stream>>>(wT, wh2, 3, S2);
        interp_wT<<<3 * S3,  256, 0, stream>>>(wT, wh3, 3, S3);

        // analysis (reads H before pw overwrites it; dwt L1 overwrites wT after interps)
        dwt2d<<<dim3((S1 + 15) / 16, (S1 + 15) / 16, 256), 256, 0, stream>>>(
            H, ll1, lh1, hl1, hh1, Hp, Hp, S1, S1);
        dwt2d<<<dim3((S2 + 15) / 16, (S2 + 15) / 16, 256), 256, 0, stream>>>(
            ll1, ll2, lh2, hl2, hh2, S1, S1, S2, S2);
        dwt2d<<<dim3((S3 + 15) / 16, (S3 + 15) / 16, 256), 256, 0, stream>>>(
            ll2, ll3, lh3, hl3, hh3, S2, S2, S3, S3);

        // u2 = pw(h) in place
        pw_inplace<<<(npix + 255) / 256, 256, 0, stream>>>(
            H, pww + (size_t)l * 1024, pwb + (size_t)l * 32, (int)HW, npix);

        // subband channel mixes (in place)
        mix_ll<<<(int)A3, 256, 0, stream>>>(ll3, wll, (int)A3);
        mix_high3<<<dim3((8 * S3 + 255) / 256, S3, 3), 256, 0, stream>>>(lh3, wh3, S3, S3, N3);
        mix_high3<<<dim3((8 * S2 + 255) / 256, S2, 3), 256, 0, stream>>>(lh2, wh2, S2, S2, N2);
        mix_high3<<<dim3((8 * S1 + 255) / 256, S1, 3), 256, 0, stream>>>(lh1, wh1, S1, S1, N1);

        // synthesis
        idwt2d<<<dim3((S2 + 31) / 32, (S2 + 31) / 32, 256), 256, 0, stream>>>(
            ll3, lh3, hl3, hh3, ll2, nullptr, S3, S3, S2, S2, 0);
        idwt2d<<<dim3((S1 + 31) / 32, (S1 + 31) / 32, 256), 256, 0, stream>>>(
            ll2, lh2, hl2, hh2, ll1, nullptr, S2, S2, S1, S1, 0);
        idwt2d<<<dim3((Hp + 31) / 32, (Hp + 31) / 32, 256), 256, 0, stream>>>(
            ll1, lh1, hl1, hh1, H, H, S1, S1, Hp, Hp, (l < 3) ? 1 : 0);
    }

    head_k<<<(8 * 256 * 256 / 4 + 255) / 256, 256, 0, stream>>>(H, fc1w, fc1b, fc2w, fc2b, out);
}